// Round 8
// baseline (610.907 us; speedup 1.0000x reference)
//
#include <hip/hip_runtime.h>
#include <hip/hip_bf16.h>
#include <cstdint>
#include <cstddef>

#define N_NODES 100000
#define N_EDGES 1600000
#define NBUCK   256
#define NPB     391           // nodes per bucket; 256*391 = 100096 >= N_NODES
#define NB_E    ((N_EDGES + 4095) / 4096)   // 391 blocks, 4096 edges each
// staging pack: src (17 bits, <131072) | localdst (9 bits, <391) << 17

// mid_kernel grid layout: pass1b blocks FIRST (critical path), cvt jobs behind.
#define MID_P   NB_E                 // 391:  pass1b
#define MID_X   (MID_P + 12500)      // x:  N_NODES*128/4 / 256 = 12500 blocks
#define MID_W1  (MID_X + 64)         // W1: 256*256/4  /256 = 64
#define MID_W2  (MID_W1 + 128)       // W2: 256*512/4  /256 = 128
#define MID_END (MID_W2 + 32)        // W3cat: 8192/256 = 32

typedef __attribute__((ext_vector_type(8))) short short8;
typedef __attribute__((ext_vector_type(4))) float floatx4;

__device__ inline float bf_lo(unsigned int u) { return __uint_as_float(u << 16); }
__device__ inline float bf_hi(unsigned int u) { return __uint_as_float(u & 0xffff0000u); }
__device__ inline unsigned short f2bf(float f) {
  unsigned int u = __float_as_uint(f);
  u += 0x7fffu + ((u >> 16) & 1u);   // round-nearest-even
  return (unsigned short)(u >> 16);
}

__device__ inline void cvt4_body(const float* __restrict__ in,
                                 unsigned short* __restrict__ out, int t) {
  float4 v = ((const float4*)in)[t];
  ushort4 o;
  o.x = f2bf(v.x); o.y = f2bf(v.y); o.z = f2bf(v.z); o.w = f2bf(v.w);
  ((ushort4*)out)[t] = o;
}

// ---------- pass1a: per-block bucket histogram (standalone so scanB starts after
// only 6.4 MB of reads, not the full 83 MB cvt stream) ----------
__global__ __launch_bounds__(256)
void pass1a_kernel(const int* __restrict__ dst, int* __restrict__ blockHist) {
  __shared__ int hist[NBUCK];
  const int b = blockIdx.x, tid = threadIdx.x;
  hist[tid] = 0;                       // NBUCK == blockDim == 256
  __syncthreads();
#pragma unroll
  for (int i = 0; i < 16; ++i) {
    int e = b * 4096 + i * 256 + tid;
    if (e < N_EDGES) atomicAdd(&hist[dst[e] / NPB], 1);
  }
  __syncthreads();
  blockHist[b * NBUCK + tid] = hist[tid];
}

__device__ inline int wave_incl_scan(int v, int lane) {
#pragma unroll
  for (int off = 1; off < 64; off <<= 1) {
    int t = __shfl_up(v, off, 64);
    if (lane >= off) v += t;
  }
  return v;
}

// scanB1: one WAVE per bucket (256 waves = 64 blocks). Wave-parallel exclusive
// scan of blockHist[*][bucket] over NB_E blocks (7 chunks of 64 + carry).
__global__ __launch_bounds__(256)
void scanB1_kernel(const int* __restrict__ blockHist,
                   int* __restrict__ blockOfs, int* __restrict__ bucketCount) {
  int bucket = (int)((blockIdx.x * 256 + threadIdx.x) >> 6);
  if (bucket >= NBUCK) return;
  int lane = threadIdx.x & 63;
  int carry = 0;
  for (int c0 = 0; c0 < NB_E; c0 += 64) {
    int blk = c0 + lane;
    int v = (blk < NB_E) ? blockHist[blk * NBUCK + bucket] : 0;
    int incl = wave_incl_scan(v, lane);
    if (blk < NB_E) blockOfs[blk * NBUCK + bucket] = carry + incl - v;  // bucket-relative
    carry += __shfl(incl, 63, 64);
  }
  if (lane == 63) bucketCount[bucket] = carry;
}

// scanB2: exclusive scan of 256 bucket totals (4 waves).
__global__ void scanB2_kernel(const int* __restrict__ bucketCount,
                              int* __restrict__ bucketBase) {
  __shared__ int wsum[4];
  int t = threadIdx.x, lane = t & 63, wid = t >> 6;   // 256 threads
  int v = bucketCount[t];
  int incl = wave_incl_scan(v, lane);
  if (lane == 63) wsum[wid] = incl;
  __syncthreads();
  int off = 0;
  for (int w = 0; w < wid; ++w) off += wsum[w];
  bucketBase[t] = off + incl - v;
  if (t == NBUCK - 1) bucketBase[NBUCK] = off + incl;  // == N_EDGES
}

// ---------- mid_kernel: pass1b (staging scatter) + all bf16 cvts ----------
// pass1b blocks get low indices (resident first, they gate pass2); the ~13us of
// cvt streaming fills CUs behind them. All jobs 256-thread, low-VGPR.
__global__ __launch_bounds__(256)
void mid_kernel(const int* __restrict__ src, const int* __restrict__ dst,
                const int* __restrict__ blockOfs, const int* __restrict__ bucketBase,
                unsigned int* __restrict__ staging,
                const float* __restrict__ x,  unsigned short* __restrict__ H0,
                const float* __restrict__ W1, unsigned short* __restrict__ Wb1,
                const float* __restrict__ W2, unsigned short* __restrict__ Wb2,
                const float* __restrict__ W3, unsigned short* __restrict__ Wb3) {
  __shared__ int hist[NBUCK];
  const int b = blockIdx.x, tid = threadIdx.x;
  if (b < MID_P) {
    // pass1b: stage packed (src|localdst) at precomputed per-(block,bucket) cursors.
    hist[tid] = bucketBase[tid] + blockOfs[b * NBUCK + tid];
    __syncthreads();
#pragma unroll
    for (int i = 0; i < 16; ++i) {
      int e = b * 4096 + i * 256 + tid;
      if (e < N_EDGES) {
        int d = dst[e];
        int bb = d / NPB;
        int pos = atomicAdd(&hist[bb], 1);           // LDS cursor
        staging[pos] = (unsigned)src[e] | ((unsigned)(d - bb * NPB) << 17);
      }
    }
  } else if (b < MID_X) {
    cvt4_body(x, H0, (b - MID_P) * 256 + tid);         // exact: 12500*256 = 3.2M
  } else if (b < MID_W1) {
    cvt4_body(W1, Wb1, (b - MID_X) * 256 + tid);       // exact: 64*256
  } else if (b < MID_W2) {
    cvt4_body(W2, Wb2, (b - MID_W1) * 256 + tid);      // exact: 128*256
  } else {
    // W3 (64 x 512 fp32) -> Wcat (128 x 256 bf16): rows 0-63 self, 64-127 neigh
    int t = (b - MID_W2) * 256 + tid;                  // exact: 32*256 = 8192
    int idx4 = t * 4;
    int r = idx4 >> 8, c = idx4 & 255;
    float4 v = *(const float4*)(W3 + (size_t)(r & 63) * 512 + (r >> 6) * 256 + c);
    ushort4 o;
    o.x = f2bf(v.x); o.y = f2bf(v.y); o.z = f2bf(v.z); o.w = f2bf(v.w);
    *(ushort4*)(Wb3 + (size_t)r * 256 + c) = o;
  }
}

// pass2: one block per bucket (256 blocks x 512 threads -> all 256 CUs).
// One node per thread (NPB=391<=512).
__global__ __launch_bounds__(512)
void pass2_kernel(const unsigned int* __restrict__ staging, const int* __restrict__ bucketBase,
                  int* __restrict__ start, float* __restrict__ invdeg,
                  int* __restrict__ esrc) {
  __shared__ int cnt[512];
  __shared__ int cur[512];
  __shared__ int wsum[8];
  const int b = blockIdx.x, tid = threadIdx.x;
  const int lane = tid & 63, wid = tid >> 6;          // 8 waves
  const int n0 = b * NPB, n1 = min(n0 + NPB, N_NODES);
  const int nLocal = n1 - n0;
  const int p0 = bucketBase[b], p1 = bucketBase[b + 1];

  cnt[tid] = 0;
  __syncthreads();
  for (int e = p0 + tid; e < p1; e += 512)
    atomicAdd(&cnt[staging[e] >> 17], 1);
  __syncthreads();

  int c = cnt[tid];
  int incl = wave_incl_scan(c, lane);
  if (lane == 63) wsum[wid] = incl;
  __syncthreads();
  if (wid == 0) {
    int v = (lane < 8) ? wsum[lane] : 0;
    int i2 = wave_incl_scan(v, lane);
    if (lane < 8) wsum[lane] = i2 - v;   // exclusive
  }
  __syncthreads();
  int excl = wsum[wid] + incl - c;
  cur[tid] = excl;
  if (tid < nLocal) {
    start[n0 + tid] = p0 + excl;
    invdeg[n0 + tid] = 1.0f / fmaxf((float)c, 1.0f);
  }
  if (b == NBUCK - 1 && tid == 0) start[N_NODES] = N_EDGES;
  __syncthreads();

  for (int e = p0 + tid; e < p1; e += 512) {
    unsigned int pr = staging[e];
    int pos = p0 + atomicAdd(&cur[pr >> 17], 1);
    esrc[pos] = (int)(pr & 0x1FFFFu);
  }
}

// ---------- gather-mean: hn[n] = mean over incoming edges of h[src] ----------
// One wave per dst node. Fabric-bound at ~3.8 TB/s beyond-L2 (verified: FETCH_SIZE
// matches the 7-of-8-XCD duplication model; stable 113.3us/3.87TB/s across rounds).
// Overlap with GEMM was tried (R1) and REGRESSED. Keep serial; do not touch.
template<int D>
__global__ __launch_bounds__(256)
void gather_mean(const unsigned short* __restrict__ h,
                 const int* __restrict__ start,
                 const int* __restrict__ esrc,
                 const float* __restrict__ invdeg,
                 unsigned short* __restrict__ hn) {
  int wave = (int)((blockIdx.x * 256 + threadIdx.x) >> 6);
  if (wave >= N_NODES) return;
  int lane = threadIdx.x & 63;
  int s0 = start[wave], s1 = start[wave + 1];
  constexpr int FPL = D / 64;           // 2 (D=128) or 4 (D=256)
  float acc[FPL] = {};
  const unsigned short* base = h + lane * FPL;

  int e = s0;
  if constexpr (FPL == 4) {
    for (; e + 4 <= s1; e += 4) {
      int sn0 = esrc[e], sn1 = esrc[e + 1], sn2 = esrc[e + 2], sn3 = esrc[e + 3];
      uint2 p0 = *(const uint2*)(base + (size_t)sn0 * D);
      uint2 p1 = *(const uint2*)(base + (size_t)sn1 * D);
      uint2 p2 = *(const uint2*)(base + (size_t)sn2 * D);
      uint2 p3 = *(const uint2*)(base + (size_t)sn3 * D);
      acc[0] += bf_lo(p0.x) + bf_lo(p1.x) + bf_lo(p2.x) + bf_lo(p3.x);
      acc[1] += bf_hi(p0.x) + bf_hi(p1.x) + bf_hi(p2.x) + bf_hi(p3.x);
      acc[2] += bf_lo(p0.y) + bf_lo(p1.y) + bf_lo(p2.y) + bf_lo(p3.y);
      acc[3] += bf_hi(p0.y) + bf_hi(p1.y) + bf_hi(p2.y) + bf_hi(p3.y);
    }
    for (; e < s1; ++e) {
      int sn = esrc[e];
      uint2 p = *(const uint2*)(base + (size_t)sn * D);
      acc[0] += bf_lo(p.x); acc[1] += bf_hi(p.x);
      acc[2] += bf_lo(p.y); acc[3] += bf_hi(p.y);
    }
  } else {
    for (; e + 4 <= s1; e += 4) {
      int sn0 = esrc[e], sn1 = esrc[e + 1], sn2 = esrc[e + 2], sn3 = esrc[e + 3];
      unsigned int p0 = *(const unsigned int*)(base + (size_t)sn0 * D);
      unsigned int p1 = *(const unsigned int*)(base + (size_t)sn1 * D);
      unsigned int p2 = *(const unsigned int*)(base + (size_t)sn2 * D);
      unsigned int p3 = *(const unsigned int*)(base + (size_t)sn3 * D);
      acc[0] += bf_lo(p0) + bf_lo(p1) + bf_lo(p2) + bf_lo(p3);
      acc[1] += bf_hi(p0) + bf_hi(p1) + bf_hi(p2) + bf_hi(p3);
    }
    for (; e < s1; ++e) {
      int sn = esrc[e];
      unsigned int p = *(const unsigned int*)(base + (size_t)sn * D);
      acc[0] += bf_lo(p); acc[1] += bf_hi(p);
    }
  }

  float inv = invdeg[wave];
  unsigned short* out = hn + (size_t)wave * D + lane * FPL;
  if constexpr (FPL == 4) {
    ushort4 o;
    o.x = f2bf(acc[0] * inv); o.y = f2bf(acc[1] * inv);
    o.z = f2bf(acc[2] * inv); o.w = f2bf(acc[3] * inv);
    *(ushort4*)out = o;
  } else {
    ushort2 o;
    o.x = f2bf(acc[0] * inv); o.y = f2bf(acc[1] * inv);
    *(ushort2*)out = o;
  }
}

// ---------- gather_add64: out[n,:] += invdeg * sum of Y3[src,:]  (64 fp32 cols) ----
// 16 lanes per edge (uint2 = 4 bf16 cols/lane), 4 edge-slots/wave, 4-deep unroll.
__global__ __launch_bounds__(256)
void gather_add64(const unsigned short* __restrict__ Y3,
                  const int* __restrict__ start, const int* __restrict__ esrc,
                  const float* __restrict__ invdeg, float* __restrict__ out) {
  int wave = (int)((blockIdx.x * 256 + threadIdx.x) >> 6);
  if (wave >= N_NODES) return;
  int lane = threadIdx.x & 63;
  int slot = lane >> 4, l16 = lane & 15;
  int s0 = start[wave], s1 = start[wave + 1];
  const unsigned short* ybase = Y3 + 4 * l16;       // cols [4*l16, 4*l16+4)
  float a0 = 0.f, a1 = 0.f, a2 = 0.f, a3 = 0.f;
  int e = s0 + slot;
  for (; e + 12 < s1; e += 16) {                    // slots cover e, e+4, e+8, e+12
    int sn0 = esrc[e], sn1 = esrc[e + 4], sn2 = esrc[e + 8], sn3 = esrc[e + 12];
    uint2 p0 = *(const uint2*)(ybase + (size_t)sn0 * 64);
    uint2 p1 = *(const uint2*)(ybase + (size_t)sn1 * 64);
    uint2 p2 = *(const uint2*)(ybase + (size_t)sn2 * 64);
    uint2 p3 = *(const uint2*)(ybase + (size_t)sn3 * 64);
    a0 += bf_lo(p0.x) + bf_lo(p1.x) + bf_lo(p2.x) + bf_lo(p3.x);
    a1 += bf_hi(p0.x) + bf_hi(p1.x) + bf_hi(p2.x) + bf_hi(p3.x);
    a2 += bf_lo(p0.y) + bf_lo(p1.y) + bf_lo(p2.y) + bf_lo(p3.y);
    a3 += bf_hi(p0.y) + bf_hi(p1.y) + bf_hi(p2.y) + bf_hi(p3.y);
  }
  for (; e < s1; e += 4) {                          // 4-slot-parallel tail
    uint2 p = *(const uint2*)(ybase + (size_t)esrc[e] * 64);
    a0 += bf_lo(p.x); a1 += bf_hi(p.x);
    a2 += bf_lo(p.y); a3 += bf_hi(p.y);
  }
  a0 += __shfl_xor(a0, 16, 64); a1 += __shfl_xor(a1, 16, 64);
  a2 += __shfl_xor(a2, 16, 64); a3 += __shfl_xor(a3, 16, 64);
  a0 += __shfl_xor(a0, 32, 64); a1 += __shfl_xor(a1, 32, 64);
  a2 += __shfl_xor(a2, 32, 64); a3 += __shfl_xor(a3, 32, 64);
  if (slot == 0) {
    float inv = invdeg[wave];
    float4* q = (float4*)(out + (size_t)wave * 64 + 4 * l16);
    float4 v = *q;
    v.x += inv * a0; v.y += inv * a1; v.z += inv * a2; v.w += inv * a3;
    *q = v;
  }
}

// ---------- LDS double-buffered fused GEMM ----------
// MODE 0: out = [H | HN] @ Wb^T + bias (optional relu), K = 2D.
//   R8: BN=256 single-y (was BN=128 x 2 y-blocks -> every A-row fetched from HBM
//   twice, ~780 dispatch slots apart, guaranteed L2 miss; halves A traffic).
// MODE 1: K = D (reads H only), Wb is 128 x D (rows 0-63 self, 64-127 neigh);
//         cols 0-63 -> d_out fp32 (+bias), cols 64-127 -> Y3 bf16.
template<int D, int DOUT, int BN, bool RELU, bool OUTF32, int MODE>
__global__ __launch_bounds__(256)
void sage_gemm(const unsigned short* __restrict__ H,
               const unsigned short* __restrict__ HN,
               const unsigned short* __restrict__ Wb,
               const float* __restrict__ bias,
               void* __restrict__ outp,
               unsigned short* __restrict__ y3) {
  constexpr int K   = (MODE == 1) ? D : 2 * D;
  constexpr int BM  = 128, KC = 32;
  constexpr int NCHUNK = K / KC;
  constexpr int AF  = BM / 16;
  constexpr int BF  = BN / 16;
  constexpr int FR  = AF + BF;      // 24 for BN=256, 16 for BN=128
  constexpr int NMF = 4;
  constexpr int NJF = BF / 2;       // 8 for BN=256

  __shared__ __align__(16) unsigned short lds0[FR * 512];
  __shared__ __align__(16) unsigned short lds1[FR * 512];

  const int tid  = threadIdx.x;
  const int wave = tid >> 6, lane = tid & 63;
  const int l16  = lane & 15, quad = lane >> 4;
  const int n0   = blockIdx.x * BM;
  const int bn0  = blockIdx.y * BN;
  const int wm   = wave >> 1, wn = wave & 1;

  floatx4 acc[NMF][NJF] = {};

  auto stage = [&](int c, unsigned short* buf) {
    const int kc = c * KC;
    const unsigned short* srcH = (kc < D) ? H : HN;
    const int kb = (kc < D) ? kc : kc - D;
    const int w0 = __builtin_amdgcn_readfirstlane(wave);
#pragma unroll
    for (int i = 0; i < FR / 4; ++i) {
      const int fu = w0 + 4 * i;
      const unsigned short* g;
      if (fu < AF) {
        int row = min(n0 + fu * 16 + l16, N_NODES - 1);
        g = srcH + (size_t)row * D + kb + quad * 8;
      } else {
        int col = bn0 + (fu - AF) * 16 + l16;
        g = Wb + (size_t)col * K + kc + quad * 8;
      }
      __builtin_amdgcn_global_load_lds(
          (const __attribute__((address_space(1))) unsigned int*)g,
          (__attribute__((address_space(3))) unsigned int*)(buf + fu * 512),
          16, 0, 0);
    }
  };

  auto compute = [&](const unsigned short* buf) {
    short8 b[NJF];
#pragma unroll
    for (int jt = 0; jt < NJF; ++jt)
      b[jt] = *(const short8*)(buf + (AF + wn * NJF + jt) * 512 + lane * 8);
#pragma unroll
    for (int mi = 0; mi < NMF; ++mi) {
      short8 a = *(const short8*)(buf + (wm * NMF + mi) * 512 + lane * 8);
#pragma unroll
      for (int jt = 0; jt < NJF; ++jt)
        acc[mi][jt] = __builtin_amdgcn_mfma_f32_16x16x32_bf16(a, b[jt], acc[mi][jt], 0, 0, 0);
    }
  };

  stage(0, lds0);
  __syncthreads();
#pragma unroll 1
  for (int c = 0; c < NCHUNK; c += 2) {
    stage(c + 1, lds1);
    compute(lds0);
    __syncthreads();
    if (c + 2 < NCHUNK) stage(c + 2, lds0);
    compute(lds1);
    __syncthreads();
  }

#pragma unroll
  for (int mi = 0; mi < NMF; ++mi) {
#pragma unroll
    for (int jt = 0; jt < NJF; ++jt) {
      int j = bn0 + wn * (NJF * 16) + jt * 16 + l16;
      float bj = (MODE == 1 && wn == 1) ? 0.0f : bias[j];
#pragma unroll
      for (int r = 0; r < 4; ++r) {
        int node = n0 + wm * 64 + mi * 16 + quad * 4 + r;
        if (node < N_NODES) {
          float v = acc[mi][jt][r];
          if constexpr (MODE == 1) {
            if (wn == 0) ((float*)outp)[(size_t)node * 64 + j] = v + bj;
            else y3[(size_t)node * 64 + (j - 64)] = f2bf(v);
          } else {
            v += bj;
            if (RELU) v = fmaxf(v, 0.0f);
            if (OUTF32) ((float*)outp)[(size_t)node * DOUT + j] = v;
            else ((unsigned short*)outp)[(size_t)node * DOUT + j] = f2bf(v);
          }
        }
      }
    }
  }
}

extern "C" void kernel_launch(void* const* d_in, const int* in_sizes, int n_in,
                              void* d_out, int out_size, void* d_ws, size_t ws_size,
                              hipStream_t stream) {
  const float* x   = (const float*)d_in[0];
  const int*   src = (const int*)d_in[1];
  const int*   dst = (const int*)d_in[2];
  const float* W1 = (const float*)d_in[3];
  const float* b1 = (const float*)d_in[4];
  const float* W2 = (const float*)d_in[5];
  const float* b2 = (const float*)d_in[6];
  const float* W3 = (const float*)d_in[7];
  const float* b3 = (const float*)d_in[8];

  char* ws = (char*)d_ws;
  unsigned short* H0 = (unsigned short*)ws; ws += (size_t)N_NODES * 128 * 2; // 25.6 MB
  unsigned short* H1 = (unsigned short*)ws; ws += (size_t)N_NODES * 256 * 2; // 51.2 MB
  unsigned short* H2 = (unsigned short*)ws; ws += (size_t)N_NODES * 256 * 2; // 51.2 MB
  unsigned short* HN = (unsigned short*)ws; ws += (size_t)N_NODES * 256 * 2; // 51.2 MB
  unsigned int* staging = (unsigned int*)ws; ws += (size_t)N_EDGES * 4;      // 6.4 MB (packed)
  int* esrc   = (int*)ws;  ws += (size_t)N_EDGES * 4;                        // 6.4 MB
  int* startp = (int*)ws;  ws += (size_t)(N_NODES + 32) * 4;
  float* invdeg = (float*)ws; ws += (size_t)(N_NODES + 32) * 4;
  int* bucketBase  = (int*)ws; ws += (NBUCK + 32) * 4;
  int* bucketCount = (int*)ws; ws += NBUCK * 4;
  int* blockHist   = (int*)ws; ws += (size_t)NB_E * NBUCK * 4;   // 400 KB
  int* blockOfs    = (int*)ws; ws += (size_t)NB_E * NBUCK * 4;   // 400 KB
  unsigned short* Y3 = (unsigned short*)ws; ws += (size_t)N_NODES * 64 * 2;  // 12.8 MB
  unsigned short* Wb1 = (unsigned short*)ws; ws += 256 * 256 * 2;
  unsigned short* Wb2 = (unsigned short*)ws; ws += 256 * 512 * 2;
  unsigned short* Wb3 = (unsigned short*)ws; ws += 128 * 256 * 2;

  // CSR build: histogram -> 2-level scan -> {staging scatter || bf16 cvts} -> sort
  pass1a_kernel<<<NB_E, 256, 0, stream>>>(dst, blockHist);
  scanB1_kernel<<<(NBUCK * 64 + 255) / 256, 256, 0, stream>>>(blockHist, blockOfs, bucketCount);
  scanB2_kernel<<<1, NBUCK, 0, stream>>>(bucketCount, bucketBase);
  mid_kernel<<<MID_END, 256, 0, stream>>>(src, dst, blockOfs, bucketBase, staging,
                                          x, H0, W1, Wb1, W2, Wb2, W3, Wb3);
  pass2_kernel<<<NBUCK, 512, 0, stream>>>(staging, bucketBase, startp, invdeg, esrc);

  const int GGRID = (N_NODES * 64 + 255) / 256;    // one wave per node
  const int MG = (N_NODES + 127) / 128;            // 782 M-tiles

  // ---- layer 1: D=128 -> 256, relu ----
  gather_mean<128><<<GGRID, 256, 0, stream>>>(H0, startp, esrc, invdeg, HN);
  sage_gemm<128, 256, 256, true, false, 0><<<MG, 256, 0, stream>>>(H0, HN, Wb1, b1, H1, nullptr);

  // ---- layer 2: D=256 -> 256, relu ----
  gather_mean<256><<<GGRID, 256, 0, stream>>>(H1, startp, esrc, invdeg, HN);
  sage_gemm<256, 256, 256, true, false, 0><<<MG, 256, 0, stream>>>(H1, HN, Wb2, b2, H2, nullptr);

  // ---- layer 3 (aggregate after GEMM): dual GEMM then edge-mean on 64 cols ----
  sage_gemm<256, 128, 128, false, true, 1><<<MG, 256, 0, stream>>>(H2, nullptr, Wb3, b3, (float*)d_out, Y3);
  gather_add64<<<GGRID, 256, 0, stream>>>(Y3, startp, esrc, invdeg, (float*)d_out);
}

// Round 9
// 555.005 us; speedup vs baseline: 1.1007x; 1.1007x over previous
//
#include <hip/hip_runtime.h>
#include <hip/hip_bf16.h>
#include <cstdint>
#include <cstddef>

#define N_NODES 100000
#define N_EDGES 1600000
#define NBUCK   256
#define NPB     391           // nodes per bucket; 256*391 = 100096 >= N_NODES
#define NB_E    ((N_EDGES + 4095) / 4096)   // 391 blocks, 4096 edges each
// staging pack: src (17 bits, <131072) | localdst (9 bits, <391) << 17

// mid_kernel grid layout: pass1b blocks FIRST (critical path), cvt jobs behind.
#define MID_P   NB_E                 // 391:  pass1b
#define MID_X   (MID_P + 12500)      // x:  N_NODES*128/4 / 256 = 12500 blocks
#define MID_W1  (MID_X + 64)         // W1: 256*256/4  /256 = 64
#define MID_W2  (MID_W1 + 128)       // W2: 256*512/4  /256 = 128
#define MID_END (MID_W2 + 32)        // W3cat: 8192/256 = 32

typedef __attribute__((ext_vector_type(8))) short short8;
typedef __attribute__((ext_vector_type(4))) float floatx4;

__device__ inline float bf_lo(unsigned int u) { return __uint_as_float(u << 16); }
__device__ inline float bf_hi(unsigned int u) { return __uint_as_float(u & 0xffff0000u); }
__device__ inline unsigned short f2bf(float f) {
  unsigned int u = __float_as_uint(f);
  u += 0x7fffu + ((u >> 16) & 1u);   // round-nearest-even
  return (unsigned short)(u >> 16);
}

__device__ inline void cvt4_body(const float* __restrict__ in,
                                 unsigned short* __restrict__ out, int t) {
  float4 v = ((const float4*)in)[t];
  ushort4 o;
  o.x = f2bf(v.x); o.y = f2bf(v.y); o.z = f2bf(v.z); o.w = f2bf(v.w);
  ((ushort4*)out)[t] = o;
}

// ---------- pass1a: per-block bucket histogram (standalone so scanB starts after
// only 6.4 MB of reads, not the full 83 MB cvt stream) ----------
__global__ __launch_bounds__(256)
void pass1a_kernel(const int* __restrict__ dst, int* __restrict__ blockHist) {
  __shared__ int hist[NBUCK];
  const int b = blockIdx.x, tid = threadIdx.x;
  hist[tid] = 0;                       // NBUCK == blockDim == 256
  __syncthreads();
#pragma unroll
  for (int i = 0; i < 16; ++i) {
    int e = b * 4096 + i * 256 + tid;
    if (e < N_EDGES) atomicAdd(&hist[dst[e] / NPB], 1);
  }
  __syncthreads();
  blockHist[b * NBUCK + tid] = hist[tid];
}

__device__ inline int wave_incl_scan(int v, int lane) {
#pragma unroll
  for (int off = 1; off < 64; off <<= 1) {
    int t = __shfl_up(v, off, 64);
    if (lane >= off) v += t;
  }
  return v;
}

// scanB1: one WAVE per bucket (256 waves = 64 blocks). Wave-parallel exclusive
// scan of blockHist[*][bucket] over NB_E blocks (7 chunks of 64 + carry).
__global__ __launch_bounds__(256)
void scanB1_kernel(const int* __restrict__ blockHist,
                   int* __restrict__ blockOfs, int* __restrict__ bucketCount) {
  int bucket = (int)((blockIdx.x * 256 + threadIdx.x) >> 6);
  if (bucket >= NBUCK) return;
  int lane = threadIdx.x & 63;
  int carry = 0;
  for (int c0 = 0; c0 < NB_E; c0 += 64) {
    int blk = c0 + lane;
    int v = (blk < NB_E) ? blockHist[blk * NBUCK + bucket] : 0;
    int incl = wave_incl_scan(v, lane);
    if (blk < NB_E) blockOfs[blk * NBUCK + bucket] = carry + incl - v;  // bucket-relative
    carry += __shfl(incl, 63, 64);
  }
  if (lane == 63) bucketCount[bucket] = carry;
}

// scanB2: exclusive scan of 256 bucket totals (4 waves).
__global__ void scanB2_kernel(const int* __restrict__ bucketCount,
                              int* __restrict__ bucketBase) {
  __shared__ int wsum[4];
  int t = threadIdx.x, lane = t & 63, wid = t >> 6;   // 256 threads
  int v = bucketCount[t];
  int incl = wave_incl_scan(v, lane);
  if (lane == 63) wsum[wid] = incl;
  __syncthreads();
  int off = 0;
  for (int w = 0; w < wid; ++w) off += wsum[w];
  bucketBase[t] = off + incl - v;
  if (t == NBUCK - 1) bucketBase[NBUCK] = off + incl;  // == N_EDGES
}

// ---------- mid_kernel: pass1b (staging scatter) + all bf16 cvts ----------
// pass1b blocks get low indices (resident first, they gate pass2); the ~13us of
// cvt streaming fills CUs behind them. All jobs 256-thread, low-VGPR.
__global__ __launch_bounds__(256)
void mid_kernel(const int* __restrict__ src, const int* __restrict__ dst,
                const int* __restrict__ blockOfs, const int* __restrict__ bucketBase,
                unsigned int* __restrict__ staging,
                const float* __restrict__ x,  unsigned short* __restrict__ H0,
                const float* __restrict__ W1, unsigned short* __restrict__ Wb1,
                const float* __restrict__ W2, unsigned short* __restrict__ Wb2,
                const float* __restrict__ W3, unsigned short* __restrict__ Wb3) {
  __shared__ int hist[NBUCK];
  const int b = blockIdx.x, tid = threadIdx.x;
  if (b < MID_P) {
    // pass1b: stage packed (src|localdst) at precomputed per-(block,bucket) cursors.
    hist[tid] = bucketBase[tid] + blockOfs[b * NBUCK + tid];
    __syncthreads();
#pragma unroll
    for (int i = 0; i < 16; ++i) {
      int e = b * 4096 + i * 256 + tid;
      if (e < N_EDGES) {
        int d = dst[e];
        int bb = d / NPB;
        int pos = atomicAdd(&hist[bb], 1);           // LDS cursor
        staging[pos] = (unsigned)src[e] | ((unsigned)(d - bb * NPB) << 17);
      }
    }
  } else if (b < MID_X) {
    cvt4_body(x, H0, (b - MID_P) * 256 + tid);         // exact: 12500*256 = 3.2M
  } else if (b < MID_W1) {
    cvt4_body(W1, Wb1, (b - MID_X) * 256 + tid);       // exact: 64*256
  } else if (b < MID_W2) {
    cvt4_body(W2, Wb2, (b - MID_W1) * 256 + tid);      // exact: 128*256
  } else {
    // W3 (64 x 512 fp32) -> Wcat (128 x 256 bf16): rows 0-63 self, 64-127 neigh
    int t = (b - MID_W2) * 256 + tid;                  // exact: 32*256 = 8192
    int idx4 = t * 4;
    int r = idx4 >> 8, c = idx4 & 255;
    float4 v = *(const float4*)(W3 + (size_t)(r & 63) * 512 + (r >> 6) * 256 + c);
    ushort4 o;
    o.x = f2bf(v.x); o.y = f2bf(v.y); o.z = f2bf(v.z); o.w = f2bf(v.w);
    *(ushort4*)(Wb3 + (size_t)r * 256 + c) = o;
  }
}

// pass2: one block per bucket (256 blocks x 512 threads -> all 256 CUs).
// One node per thread (NPB=391<=512).
__global__ __launch_bounds__(512)
void pass2_kernel(const unsigned int* __restrict__ staging, const int* __restrict__ bucketBase,
                  int* __restrict__ start, float* __restrict__ invdeg,
                  int* __restrict__ esrc) {
  __shared__ int cnt[512];
  __shared__ int cur[512];
  __shared__ int wsum[8];
  const int b = blockIdx.x, tid = threadIdx.x;
  const int lane = tid & 63, wid = tid >> 6;          // 8 waves
  const int n0 = b * NPB, n1 = min(n0 + NPB, N_NODES);
  const int nLocal = n1 - n0;
  const int p0 = bucketBase[b], p1 = bucketBase[b + 1];

  cnt[tid] = 0;
  __syncthreads();
  for (int e = p0 + tid; e < p1; e += 512)
    atomicAdd(&cnt[staging[e] >> 17], 1);
  __syncthreads();

  int c = cnt[tid];
  int incl = wave_incl_scan(c, lane);
  if (lane == 63) wsum[wid] = incl;
  __syncthreads();
  if (wid == 0) {
    int v = (lane < 8) ? wsum[lane] : 0;
    int i2 = wave_incl_scan(v, lane);
    if (lane < 8) wsum[lane] = i2 - v;   // exclusive
  }
  __syncthreads();
  int excl = wsum[wid] + incl - c;
  cur[tid] = excl;
  if (tid < nLocal) {
    start[n0 + tid] = p0 + excl;
    invdeg[n0 + tid] = 1.0f / fmaxf((float)c, 1.0f);
  }
  if (b == NBUCK - 1 && tid == 0) start[N_NODES] = N_EDGES;
  __syncthreads();

  for (int e = p0 + tid; e < p1; e += 512) {
    unsigned int pr = staging[e];
    int pos = p0 + atomicAdd(&cur[pr >> 17], 1);
    esrc[pos] = (int)(pr & 0x1FFFFu);
  }
}

// ---------- gather-mean: hn[n] = mean over incoming edges of h[src] ----------
// One wave per dst node. Fabric-bound at ~3.8 TB/s beyond-L2 (verified: FETCH_SIZE
// matches the 7-of-8-XCD duplication model; stable 113.3us/3.87TB/s across rounds).
// Overlap with GEMM was tried (R1) and REGRESSED. Keep serial; do not touch.
template<int D>
__global__ __launch_bounds__(256)
void gather_mean(const unsigned short* __restrict__ h,
                 const int* __restrict__ start,
                 const int* __restrict__ esrc,
                 const float* __restrict__ invdeg,
                 unsigned short* __restrict__ hn) {
  int wave = (int)((blockIdx.x * 256 + threadIdx.x) >> 6);
  if (wave >= N_NODES) return;
  int lane = threadIdx.x & 63;
  int s0 = start[wave], s1 = start[wave + 1];
  constexpr int FPL = D / 64;           // 2 (D=128) or 4 (D=256)
  float acc[FPL] = {};
  const unsigned short* base = h + lane * FPL;

  int e = s0;
  if constexpr (FPL == 4) {
    for (; e + 4 <= s1; e += 4) {
      int sn0 = esrc[e], sn1 = esrc[e + 1], sn2 = esrc[e + 2], sn3 = esrc[e + 3];
      uint2 p0 = *(const uint2*)(base + (size_t)sn0 * D);
      uint2 p1 = *(const uint2*)(base + (size_t)sn1 * D);
      uint2 p2 = *(const uint2*)(base + (size_t)sn2 * D);
      uint2 p3 = *(const uint2*)(base + (size_t)sn3 * D);
      acc[0] += bf_lo(p0.x) + bf_lo(p1.x) + bf_lo(p2.x) + bf_lo(p3.x);
      acc[1] += bf_hi(p0.x) + bf_hi(p1.x) + bf_hi(p2.x) + bf_hi(p3.x);
      acc[2] += bf_lo(p0.y) + bf_lo(p1.y) + bf_lo(p2.y) + bf_lo(p3.y);
      acc[3] += bf_hi(p0.y) + bf_hi(p1.y) + bf_hi(p2.y) + bf_hi(p3.y);
    }
    for (; e < s1; ++e) {
      int sn = esrc[e];
      uint2 p = *(const uint2*)(base + (size_t)sn * D);
      acc[0] += bf_lo(p.x); acc[1] += bf_hi(p.x);
      acc[2] += bf_lo(p.y); acc[3] += bf_hi(p.y);
    }
  } else {
    for (; e + 4 <= s1; e += 4) {
      int sn0 = esrc[e], sn1 = esrc[e + 1], sn2 = esrc[e + 2], sn3 = esrc[e + 3];
      unsigned int p0 = *(const unsigned int*)(base + (size_t)sn0 * D);
      unsigned int p1 = *(const unsigned int*)(base + (size_t)sn1 * D);
      unsigned int p2 = *(const unsigned int*)(base + (size_t)sn2 * D);
      unsigned int p3 = *(const unsigned int*)(base + (size_t)sn3 * D);
      acc[0] += bf_lo(p0) + bf_lo(p1) + bf_lo(p2) + bf_lo(p3);
      acc[1] += bf_hi(p0) + bf_hi(p1) + bf_hi(p2) + bf_hi(p3);
    }
    for (; e < s1; ++e) {
      int sn = esrc[e];
      unsigned int p = *(const unsigned int*)(base + (size_t)sn * D);
      acc[0] += bf_lo(p); acc[1] += bf_hi(p);
    }
  }

  float inv = invdeg[wave];
  unsigned short* out = hn + (size_t)wave * D + lane * FPL;
  if constexpr (FPL == 4) {
    ushort4 o;
    o.x = f2bf(acc[0] * inv); o.y = f2bf(acc[1] * inv);
    o.z = f2bf(acc[2] * inv); o.w = f2bf(acc[3] * inv);
    *(ushort4*)out = o;
  } else {
    ushort2 o;
    o.x = f2bf(acc[0] * inv); o.y = f2bf(acc[1] * inv);
    *(ushort2*)out = o;
  }
}

// ---------- gather_add64: out[n,:] += invdeg * sum of Y3[src,:]  (64 fp32 cols) ----
// 16 lanes per edge (uint2 = 4 bf16 cols/lane), 4 edge-slots/wave, 4-deep unroll.
__global__ __launch_bounds__(256)
void gather_add64(const unsigned short* __restrict__ Y3,
                  const int* __restrict__ start, const int* __restrict__ esrc,
                  const float* __restrict__ invdeg, float* __restrict__ out) {
  int wave = (int)((blockIdx.x * 256 + threadIdx.x) >> 6);
  if (wave >= N_NODES) return;
  int lane = threadIdx.x & 63;
  int slot = lane >> 4, l16 = lane & 15;
  int s0 = start[wave], s1 = start[wave + 1];
  const unsigned short* ybase = Y3 + 4 * l16;       // cols [4*l16, 4*l16+4)
  float a0 = 0.f, a1 = 0.f, a2 = 0.f, a3 = 0.f;
  int e = s0 + slot;
  for (; e + 12 < s1; e += 16) {                    // slots cover e, e+4, e+8, e+12
    int sn0 = esrc[e], sn1 = esrc[e + 4], sn2 = esrc[e + 8], sn3 = esrc[e + 12];
    uint2 p0 = *(const uint2*)(ybase + (size_t)sn0 * 64);
    uint2 p1 = *(const uint2*)(ybase + (size_t)sn1 * 64);
    uint2 p2 = *(const uint2*)(ybase + (size_t)sn2 * 64);
    uint2 p3 = *(const uint2*)(ybase + (size_t)sn3 * 64);
    a0 += bf_lo(p0.x) + bf_lo(p1.x) + bf_lo(p2.x) + bf_lo(p3.x);
    a1 += bf_hi(p0.x) + bf_hi(p1.x) + bf_hi(p2.x) + bf_hi(p3.x);
    a2 += bf_lo(p0.y) + bf_lo(p1.y) + bf_lo(p2.y) + bf_lo(p3.y);
    a3 += bf_hi(p0.y) + bf_hi(p1.y) + bf_hi(p2.y) + bf_hi(p3.y);
  }
  for (; e < s1; e += 4) {                          // 4-slot-parallel tail
    uint2 p = *(const uint2*)(ybase + (size_t)esrc[e] * 64);
    a0 += bf_lo(p.x); a1 += bf_hi(p.x);
    a2 += bf_lo(p.y); a3 += bf_hi(p.y);
  }
  a0 += __shfl_xor(a0, 16, 64); a1 += __shfl_xor(a1, 16, 64);
  a2 += __shfl_xor(a2, 16, 64); a3 += __shfl_xor(a3, 16, 64);
  a0 += __shfl_xor(a0, 32, 64); a1 += __shfl_xor(a1, 32, 64);
  a2 += __shfl_xor(a2, 32, 64); a3 += __shfl_xor(a3, 32, 64);
  if (slot == 0) {
    float inv = invdeg[wave];
    float4* q = (float4*)(out + (size_t)wave * 64 + 4 * l16);
    float4 v = *q;
    v.x += inv * a0; v.y += inv * a1; v.z += inv * a2; v.w += inv * a3;
    *q = v;
  }
}

// ---------- LDS double-buffered fused GEMM ----------
// R9: back to BN=128 (R8's BN=256 collapsed occupancy to 8.7% -> 116us, latency-
// bound; FETCH halved but time doubled). N-blocks now FASTEST-varying grid dim
// (dim3(NB, MG), n0 from blockIdx.y) so the 2 blocks sharing an A-panel are
// dispatch-adjacent -> the pair's A-reads land in L2/LLC together (traffic win
// without the occupancy cost).
// MODE 0: out = [H | HN] @ Wb^T + bias (optional relu), K = 2D.
// MODE 1: K = D (reads H only), Wb is 128 x D (rows 0-63 self, 64-127 neigh);
//         cols 0-63 -> d_out fp32 (+bias), cols 64-127 -> Y3 bf16.
template<int D, int DOUT, int BN, bool RELU, bool OUTF32, int MODE>
__global__ __launch_bounds__(256)
void sage_gemm(const unsigned short* __restrict__ H,
               const unsigned short* __restrict__ HN,
               const unsigned short* __restrict__ Wb,
               const float* __restrict__ bias,
               void* __restrict__ outp,
               unsigned short* __restrict__ y3) {
  constexpr int K   = (MODE == 1) ? D : 2 * D;
  constexpr int BM  = 128, KC = 32;
  constexpr int NCHUNK = K / KC;
  constexpr int AF  = BM / 16;
  constexpr int BF  = BN / 16;
  constexpr int FR  = AF + BF;
  constexpr int NMF = 4;
  constexpr int NJF = BF / 2;

  __shared__ __align__(16) unsigned short lds0[FR * 512];
  __shared__ __align__(16) unsigned short lds1[FR * 512];

  const int tid  = threadIdx.x;
  const int wave = tid >> 6, lane = tid & 63;
  const int l16  = lane & 15, quad = lane >> 4;
  const int n0   = blockIdx.y * BM;      // M-tile on y (slow)
  const int bn0  = blockIdx.x * BN;      // N-block on x (fast -> pair adjacent)
  const int wm   = wave >> 1, wn = wave & 1;

  floatx4 acc[NMF][NJF] = {};

  auto stage = [&](int c, unsigned short* buf) {
    const int kc = c * KC;
    const unsigned short* srcH = (kc < D) ? H : HN;
    const int kb = (kc < D) ? kc : kc - D;
    const int w0 = __builtin_amdgcn_readfirstlane(wave);
#pragma unroll
    for (int i = 0; i < FR / 4; ++i) {
      const int fu = w0 + 4 * i;
      const unsigned short* g;
      if (fu < AF) {
        int row = min(n0 + fu * 16 + l16, N_NODES - 1);
        g = srcH + (size_t)row * D + kb + quad * 8;
      } else {
        int col = bn0 + (fu - AF) * 16 + l16;
        g = Wb + (size_t)col * K + kc + quad * 8;
      }
      __builtin_amdgcn_global_load_lds(
          (const __attribute__((address_space(1))) unsigned int*)g,
          (__attribute__((address_space(3))) unsigned int*)(buf + fu * 512),
          16, 0, 0);
    }
  };

  auto compute = [&](const unsigned short* buf) {
    short8 b[NJF];
#pragma unroll
    for (int jt = 0; jt < NJF; ++jt)
      b[jt] = *(const short8*)(buf + (AF + wn * NJF + jt) * 512 + lane * 8);
#pragma unroll
    for (int mi = 0; mi < NMF; ++mi) {
      short8 a = *(const short8*)(buf + (wm * NMF + mi) * 512 + lane * 8);
#pragma unroll
      for (int jt = 0; jt < NJF; ++jt)
        acc[mi][jt] = __builtin_amdgcn_mfma_f32_16x16x32_bf16(a, b[jt], acc[mi][jt], 0, 0, 0);
    }
  };

  stage(0, lds0);
  __syncthreads();
#pragma unroll 1
  for (int c = 0; c < NCHUNK; c += 2) {
    stage(c + 1, lds1);
    compute(lds0);
    __syncthreads();
    if (c + 2 < NCHUNK) stage(c + 2, lds0);
    compute(lds1);
    __syncthreads();
  }

#pragma unroll
  for (int mi = 0; mi < NMF; ++mi) {
#pragma unroll
    for (int jt = 0; jt < NJF; ++jt) {
      int j = bn0 + wn * (NJF * 16) + jt * 16 + l16;
      float bj = (MODE == 1 && wn == 1) ? 0.0f : bias[j];
#pragma unroll
      for (int r = 0; r < 4; ++r) {
        int node = n0 + wm * 64 + mi * 16 + quad * 4 + r;
        if (node < N_NODES) {
          float v = acc[mi][jt][r];
          if constexpr (MODE == 1) {
            if (wn == 0) ((float*)outp)[(size_t)node * 64 + j] = v + bj;
            else y3[(size_t)node * 64 + (j - 64)] = f2bf(v);
          } else {
            v += bj;
            if (RELU) v = fmaxf(v, 0.0f);
            if (OUTF32) ((float*)outp)[(size_t)node * DOUT + j] = v;
            else ((unsigned short*)outp)[(size_t)node * DOUT + j] = f2bf(v);
          }
        }
      }
    }
  }
}

extern "C" void kernel_launch(void* const* d_in, const int* in_sizes, int n_in,
                              void* d_out, int out_size, void* d_ws, size_t ws_size,
                              hipStream_t stream) {
  const float* x   = (const float*)d_in[0];
  const int*   src = (const int*)d_in[1];
  const int*   dst = (const int*)d_in[2];
  const float* W1 = (const float*)d_in[3];
  const float* b1 = (const float*)d_in[4];
  const float* W2 = (const float*)d_in[5];
  const float* b2 = (const float*)d_in[6];
  const float* W3 = (const float*)d_in[7];
  const float* b3 = (const float*)d_in[8];

  char* ws = (char*)d_ws;
  unsigned short* H0 = (unsigned short*)ws; ws += (size_t)N_NODES * 128 * 2; // 25.6 MB
  unsigned short* H1 = (unsigned short*)ws; ws += (size_t)N_NODES * 256 * 2; // 51.2 MB
  unsigned short* H2 = (unsigned short*)ws; ws += (size_t)N_NODES * 256 * 2; // 51.2 MB
  unsigned short* HN = (unsigned short*)ws; ws += (size_t)N_NODES * 256 * 2; // 51.2 MB
  unsigned int* staging = (unsigned int*)ws; ws += (size_t)N_EDGES * 4;      // 6.4 MB (packed)
  int* esrc   = (int*)ws;  ws += (size_t)N_EDGES * 4;                        // 6.4 MB
  int* startp = (int*)ws;  ws += (size_t)(N_NODES + 32) * 4;
  float* invdeg = (float*)ws; ws += (size_t)(N_NODES + 32) * 4;
  int* bucketBase  = (int*)ws; ws += (NBUCK + 32) * 4;
  int* bucketCount = (int*)ws; ws += NBUCK * 4;
  int* blockHist   = (int*)ws; ws += (size_t)NB_E * NBUCK * 4;   // 400 KB
  int* blockOfs    = (int*)ws; ws += (size_t)NB_E * NBUCK * 4;   // 400 KB
  unsigned short* Y3 = (unsigned short*)ws; ws += (size_t)N_NODES * 64 * 2;  // 12.8 MB
  unsigned short* Wb1 = (unsigned short*)ws; ws += 256 * 256 * 2;
  unsigned short* Wb2 = (unsigned short*)ws; ws += 256 * 512 * 2;
  unsigned short* Wb3 = (unsigned short*)ws; ws += 128 * 256 * 2;

  // CSR build: histogram -> 2-level scan -> {staging scatter || bf16 cvts} -> sort
  pass1a_kernel<<<NB_E, 256, 0, stream>>>(dst, blockHist);
  scanB1_kernel<<<(NBUCK * 64 + 255) / 256, 256, 0, stream>>>(blockHist, blockOfs, bucketCount);
  scanB2_kernel<<<1, NBUCK, 0, stream>>>(bucketCount, bucketBase);
  mid_kernel<<<MID_END, 256, 0, stream>>>(src, dst, blockOfs, bucketBase, staging,
                                          x, H0, W1, Wb1, W2, Wb2, W3, Wb3);
  pass2_kernel<<<NBUCK, 512, 0, stream>>>(staging, bucketBase, startp, invdeg, esrc);

  const int GGRID = (N_NODES * 64 + 255) / 256;    // one wave per node
  const int MG = (N_NODES + 127) / 128;            // 782 M-tiles

  // ---- layer 1: D=128 -> 256, relu ----
  gather_mean<128><<<GGRID, 256, 0, stream>>>(H0, startp, esrc, invdeg, HN);
  sage_gemm<128, 256, 128, true, false, 0><<<dim3(2, MG), 256, 0, stream>>>(H0, HN, Wb1, b1, H1, nullptr);

  // ---- layer 2: D=256 -> 256, relu ----
  gather_mean<256><<<GGRID, 256, 0, stream>>>(H1, startp, esrc, invdeg, HN);
  sage_gemm<256, 256, 128, true, false, 0><<<dim3(2, MG), 256, 0, stream>>>(H1, HN, Wb2, b2, H2, nullptr);

  // ---- layer 3 (aggregate after GEMM): dual GEMM then edge-mean on 64 cols ----
  sage_gemm<256, 128, 128, false, true, 1><<<dim3(1, MG), 256, 0, stream>>>(H2, nullptr, Wb3, b3, (float*)d_out, Y3);
  gather_add64<<<GGRID, 256, 0, stream>>>(Y3, startp, esrc, invdeg, (float*)d_out);
}

// Round 12
// 527.982 us; speedup vs baseline: 1.1571x; 1.0512x over previous
//
#include <hip/hip_runtime.h>
#include <hip/hip_bf16.h>
#include <cstdint>
#include <cstddef>

#define N_NODES 100000
#define N_EDGES 1600000
#define NBUCK   256
#define NPB     391           // nodes per bucket; 256*391 = 100096 >= N_NODES
#define NB_E    ((N_EDGES + 4095) / 4096)   // 391 blocks, 4096 edges each
// staging pack: src (17 bits, <131072) | localdst (9 bits, <391) << 17

// mid_kernel grid layout: pass1b blocks FIRST (critical path), cvt jobs behind.
#define MID_P   NB_E                 // 391:  pass1b
#define MID_X   (MID_P + 12500)      // x:  N_NODES*128/4 / 256 = 12500 blocks
#define MID_W1  (MID_X + 64)         // W1: 256*256/4  /256 = 64
#define MID_W2  (MID_W1 + 128)       // W2: 256*512/4  /256 = 128
#define MID_END (MID_W2 + 32)        // W3cat: 8192/256 = 32

typedef __attribute__((ext_vector_type(8))) short short8;
typedef __attribute__((ext_vector_type(4))) float floatx4;

__device__ inline float bf_lo(unsigned int u) { return __uint_as_float(u << 16); }
__device__ inline float bf_hi(unsigned int u) { return __uint_as_float(u & 0xffff0000u); }
__device__ inline unsigned short f2bf(float f) {
  unsigned int u = __float_as_uint(f);
  u += 0x7fffu + ((u >> 16) & 1u);   // round-nearest-even
  return (unsigned short)(u >> 16);
}

// fp8 e4m3fn encode for v >= 0 (post-relu), integer-only, RNE, FTZ-proof.
// Codes < 8 (v < 2^-6) flush to 0 so decode never produces f32 denormals.
__device__ inline unsigned int f2fp8_pos(float v) {
  unsigned int b = __float_as_uint(v);
  b += 0x7ffffu + ((b >> 20) & 1u);        // RNE to 4-bit significand
  int q = (int)(b >> 20) - 960;            // rebias 127 -> 7 (960 = 120<<3)
  q = (q < 8) ? 0 : q;
  q = (q > 0x7e) ? 0x7e : q;               // clamp to 448 (max finite e4m3fn)
  return (unsigned int)q;
}

__device__ inline void cvt4_body(const float* __restrict__ in,
                                 unsigned short* __restrict__ out, int t) {
  float4 v = ((const float4*)in)[t];
  ushort4 o;
  o.x = f2bf(v.x); o.y = f2bf(v.y); o.z = f2bf(v.z); o.w = f2bf(v.w);
  ((ushort4*)out)[t] = o;
}

// ---------- pass1a: per-block bucket histogram ----------
__global__ __launch_bounds__(256)
void pass1a_kernel(const int* __restrict__ dst, int* __restrict__ blockHist) {
  __shared__ int hist[NBUCK];
  const int b = blockIdx.x, tid = threadIdx.x;
  hist[tid] = 0;                       // NBUCK == blockDim == 256
  __syncthreads();
#pragma unroll
  for (int i = 0; i < 16; ++i) {
    int e = b * 4096 + i * 256 + tid;
    if (e < N_EDGES) atomicAdd(&hist[dst[e] / NPB], 1);
  }
  __syncthreads();
  blockHist[b * NBUCK + tid] = hist[tid];
}

__device__ inline int wave_incl_scan(int v, int lane) {
#pragma unroll
  for (int off = 1; off < 64; off <<= 1) {
    int t = __shfl_up(v, off, 64);
    if (lane >= off) v += t;
  }
  return v;
}

// scanB1: one WAVE per bucket (256 waves = 64 blocks).
__global__ __launch_bounds__(256)
void scanB1_kernel(const int* __restrict__ blockHist,
                   int* __restrict__ blockOfs, int* __restrict__ bucketCount) {
  int bucket = (int)((blockIdx.x * 256 + threadIdx.x) >> 6);
  if (bucket >= NBUCK) return;
  int lane = threadIdx.x & 63;
  int carry = 0;
  for (int c0 = 0; c0 < NB_E; c0 += 64) {
    int blk = c0 + lane;
    int v = (blk < NB_E) ? blockHist[blk * NBUCK + bucket] : 0;
    int incl = wave_incl_scan(v, lane);
    if (blk < NB_E) blockOfs[blk * NBUCK + bucket] = carry + incl - v;  // bucket-relative
    carry += __shfl(incl, 63, 64);
  }
  if (lane == 63) bucketCount[bucket] = carry;
}

// scanB2: exclusive scan of 256 bucket totals (4 waves).
__global__ void scanB2_kernel(const int* __restrict__ bucketCount,
                              int* __restrict__ bucketBase) {
  __shared__ int wsum[4];
  int t = threadIdx.x, lane = t & 63, wid = t >> 6;   // 256 threads
  int v = bucketCount[t];
  int incl = wave_incl_scan(v, lane);
  if (lane == 63) wsum[wid] = incl;
  __syncthreads();
  int off = 0;
  for (int w = 0; w < wid; ++w) off += wsum[w];
  bucketBase[t] = off + incl - v;
  if (t == NBUCK - 1) bucketBase[NBUCK] = off + incl;  // == N_EDGES
}

// ---------- mid_kernel: pass1b (staging scatter) + all bf16 cvts ----------
__global__ __launch_bounds__(256)
void mid_kernel(const int* __restrict__ src, const int* __restrict__ dst,
                const int* __restrict__ blockOfs, const int* __restrict__ bucketBase,
                unsigned int* __restrict__ staging,
                const float* __restrict__ x,  unsigned short* __restrict__ H0,
                const float* __restrict__ W1, unsigned short* __restrict__ Wb1,
                const float* __restrict__ W2, unsigned short* __restrict__ Wb2,
                const float* __restrict__ W3, unsigned short* __restrict__ Wb3) {
  __shared__ int hist[NBUCK];
  const int b = blockIdx.x, tid = threadIdx.x;
  if (b < MID_P) {
    hist[tid] = bucketBase[tid] + blockOfs[b * NBUCK + tid];
    __syncthreads();
#pragma unroll
    for (int i = 0; i < 16; ++i) {
      int e = b * 4096 + i * 256 + tid;
      if (e < N_EDGES) {
        int d = dst[e];
        int bb = d / NPB;
        int pos = atomicAdd(&hist[bb], 1);           // LDS cursor
        staging[pos] = (unsigned)src[e] | ((unsigned)(d - bb * NPB) << 17);
      }
    }
  } else if (b < MID_X) {
    cvt4_body(x, H0, (b - MID_P) * 256 + tid);         // exact: 12500*256 = 3.2M
  } else if (b < MID_W1) {
    cvt4_body(W1, Wb1, (b - MID_X) * 256 + tid);       // exact: 64*256
  } else if (b < MID_W2) {
    cvt4_body(W2, Wb2, (b - MID_W1) * 256 + tid);      // exact: 128*256
  } else {
    // W3 (64 x 512 fp32) -> Wcat (128 x 256 bf16): rows 0-63 self, 64-127 neigh
    int t = (b - MID_W2) * 256 + tid;                  // exact: 32*256 = 8192
    int idx4 = t * 4;
    int r = idx4 >> 8, c = idx4 & 255;
    float4 v = *(const float4*)(W3 + (size_t)(r & 63) * 512 + (r >> 6) * 256 + c);
    ushort4 o;
    o.x = f2bf(v.x); o.y = f2bf(v.y); o.z = f2bf(v.z); o.w = f2bf(v.w);
    *(ushort4*)(Wb3 + (size_t)r * 256 + c) = o;
  }
}

// pass2: one block per bucket (256 blocks x 512 threads -> all 256 CUs).
__global__ __launch_bounds__(512)
void pass2_kernel(const unsigned int* __restrict__ staging, const int* __restrict__ bucketBase,
                  int* __restrict__ start, float* __restrict__ invdeg,
                  int* __restrict__ esrc) {
  __shared__ int cnt[512];
  __shared__ int cur[512];
  __shared__ int wsum[8];
  const int b = blockIdx.x, tid = threadIdx.x;
  const int lane = tid & 63, wid = tid >> 6;          // 8 waves
  const int n0 = b * NPB, n1 = min(n0 + NPB, N_NODES);
  const int nLocal = n1 - n0;
  const int p0 = bucketBase[b], p1 = bucketBase[b + 1];

  cnt[tid] = 0;
  __syncthreads();
  for (int e = p0 + tid; e < p1; e += 512)
    atomicAdd(&cnt[staging[e] >> 17], 1);
  __syncthreads();

  int c = cnt[tid];
  int incl = wave_incl_scan(c, lane);
  if (lane == 63) wsum[wid] = incl;
  __syncthreads();
  if (wid == 0) {
    int v = (lane < 8) ? wsum[lane] : 0;
    int i2 = wave_incl_scan(v, lane);
    if (lane < 8) wsum[lane] = i2 - v;   // exclusive
  }
  __syncthreads();
  int excl = wsum[wid] + incl - c;
  cur[tid] = excl;
  if (tid < nLocal) {
    start[n0 + tid] = p0 + excl;
    invdeg[n0 + tid] = 1.0f / fmaxf((float)c, 1.0f);
  }
  if (b == NBUCK - 1 && tid == 0) start[N_NODES] = N_EDGES;
  __syncthreads();

  for (int e = p0 + tid; e < p1; e += 512) {
    unsigned int pr = staging[e];
    int pos = p0 + atomicAdd(&cur[pr >> 17], 1);
    esrc[pos] = (int)(pr & 0x1FFFFu);
  }
}

// ---------- gather-mean (bf16 input): used for layer 1 (D=128) ----------
// Fabric-bound at ~3.8 TB/s beyond-L2 (FETCH matches 7-of-8-XCD duplication
// model). Overlap with GEMM regressed (R1). Keep serial.
template<int D>
__global__ __launch_bounds__(256)
void gather_mean(const unsigned short* __restrict__ h,
                 const int* __restrict__ start,
                 const int* __restrict__ esrc,
                 const float* __restrict__ invdeg,
                 unsigned short* __restrict__ hn) {
  int wave = (int)((blockIdx.x * 256 + threadIdx.x) >> 6);
  if (wave >= N_NODES) return;
  int lane = threadIdx.x & 63;
  int s0 = start[wave], s1 = start[wave + 1];
  constexpr int FPL = D / 64;           // 2 (D=128) or 4 (D=256)
  float acc[FPL] = {};
  const unsigned short* base = h + lane * FPL;

  int e = s0;
  if constexpr (FPL == 4) {
    for (; e + 4 <= s1; e += 4) {
      int sn0 = esrc[e], sn1 = esrc[e + 1], sn2 = esrc[e + 2], sn3 = esrc[e + 3];
      uint2 p0 = *(const uint2*)(base + (size_t)sn0 * D);
      uint2 p1 = *(const uint2*)(base + (size_t)sn1 * D);
      uint2 p2 = *(const uint2*)(base + (size_t)sn2 * D);
      uint2 p3 = *(const uint2*)(base + (size_t)sn3 * D);
      acc[0] += bf_lo(p0.x) + bf_lo(p1.x) + bf_lo(p2.x) + bf_lo(p3.x);
      acc[1] += bf_hi(p0.x) + bf_hi(p1.x) + bf_hi(p2.x) + bf_hi(p3.x);
      acc[2] += bf_lo(p0.y) + bf_lo(p1.y) + bf_lo(p2.y) + bf_lo(p3.y);
      acc[3] += bf_hi(p0.y) + bf_hi(p1.y) + bf_hi(p2.y) + bf_hi(p3.y);
    }
    for (; e < s1; ++e) {
      int sn = esrc[e];
      uint2 p = *(const uint2*)(base + (size_t)sn * D);
      acc[0] += bf_lo(p.x); acc[1] += bf_hi(p.x);
      acc[2] += bf_lo(p.y); acc[3] += bf_hi(p.y);
    }
  } else {
    for (; e + 4 <= s1; e += 4) {
      int sn0 = esrc[e], sn1 = esrc[e + 1], sn2 = esrc[e + 2], sn3 = esrc[e + 3];
      unsigned int p0 = *(const unsigned int*)(base + (size_t)sn0 * D);
      unsigned int p1 = *(const unsigned int*)(base + (size_t)sn1 * D);
      unsigned int p2 = *(const unsigned int*)(base + (size_t)sn2 * D);
      unsigned int p3 = *(const unsigned int*)(base + (size_t)sn3 * D);
      acc[0] += bf_lo(p0) + bf_lo(p1) + bf_lo(p2) + bf_lo(p3);
      acc[1] += bf_hi(p0) + bf_hi(p1) + bf_hi(p2) + bf_hi(p3);
    }
    for (; e < s1; ++e) {
      int sn = esrc[e];
      unsigned int p = *(const unsigned int*)(base + (size_t)sn * D);
      acc[0] += bf_lo(p); acc[1] += bf_hi(p);
    }
  }

  float inv = invdeg[wave];
  unsigned short* out = hn + (size_t)wave * D + lane * FPL;
  if constexpr (FPL == 4) {
    ushort4 o;
    o.x = f2bf(acc[0] * inv); o.y = f2bf(acc[1] * inv);
    o.z = f2bf(acc[2] * inv); o.w = f2bf(acc[3] * inv);
    *(ushort4*)out = o;
  } else {
    ushort2 o;
    o.x = f2bf(acc[0] * inv); o.y = f2bf(acc[1] * inv);
    *(ushort2*)out = o;
  }
}

// ---------- gather_mean_fp8: layer-2 gather over fp8 e4m3 copy of H1 ----------
// Halves the dominant kernel's bytes (819 -> 410 MB demand). H1 is post-relu
// (>=0, O(1)) -> sign bit always 0; codes are {0} U [8,0x7e] so decode is a pure
// bit-shift into the f32 exponent field + one scale multiply (no denormals, no
// HW fp8 builtins). Lane covers cols [4*lane, 4*lane+4): 4 B/lane, 64 lanes =
// full 256-col row.
__global__ __launch_bounds__(256)
void gather_mean_fp8(const unsigned char* __restrict__ hq,
                     const int* __restrict__ start,
                     const int* __restrict__ esrc,
                     const float* __restrict__ invdeg,
                     unsigned short* __restrict__ hn) {
  int wave = (int)((blockIdx.x * 256 + threadIdx.x) >> 6);
  if (wave >= N_NODES) return;
  int lane = threadIdx.x & 63;
  int s0 = start[wave], s1 = start[wave + 1];
  const float S = 0x1p120f;            // rebias 7 -> 127
  float a0 = 0.f, a1 = 0.f, a2 = 0.f, a3 = 0.f;
  const unsigned char* base = hq + lane * 4;

  int e = s0;
  for (; e + 4 <= s1; e += 4) {
    int sn0 = esrc[e], sn1 = esrc[e + 1], sn2 = esrc[e + 2], sn3 = esrc[e + 3];
    unsigned int p0 = *(const unsigned int*)(base + (size_t)sn0 * 256);
    unsigned int p1 = *(const unsigned int*)(base + (size_t)sn1 * 256);
    unsigned int p2 = *(const unsigned int*)(base + (size_t)sn2 * 256);
    unsigned int p3 = *(const unsigned int*)(base + (size_t)sn3 * 256);
    a0 += __uint_as_float((p0 << 20) & 0x07f00000u) * S
        + __uint_as_float((p1 << 20) & 0x07f00000u) * S
        + __uint_as_float((p2 << 20) & 0x07f00000u) * S
        + __uint_as_float((p3 << 20) & 0x07f00000u) * S;
    a1 += __uint_as_float((p0 << 12) & 0x07f00000u) * S
        + __uint_as_float((p1 << 12) & 0x07f00000u) * S
        + __uint_as_float((p2 << 12) & 0x07f00000u) * S
        + __uint_as_float((p3 << 12) & 0x07f00000u) * S;
    a2 += __uint_as_float((p0 << 4)  & 0x07f00000u) * S
        + __uint_as_float((p1 << 4)  & 0x07f00000u) * S
        + __uint_as_float((p2 << 4)  & 0x07f00000u) * S
        + __uint_as_float((p3 << 4)  & 0x07f00000u) * S;
    a3 += __uint_as_float((p0 >> 4)  & 0x07f00000u) * S
        + __uint_as_float((p1 >> 4)  & 0x07f00000u) * S
        + __uint_as_float((p2 >> 4)  & 0x07f00000u) * S
        + __uint_as_float((p3 >> 4)  & 0x07f00000u) * S;
  }
  for (; e < s1; ++e) {
    unsigned int p = *(const unsigned int*)(base + (size_t)esrc[e] * 256);
    a0 += __uint_as_float((p << 20) & 0x07f00000u) * S;
    a1 += __uint_as_float((p << 12) & 0x07f00000u) * S;
    a2 += __uint_as_float((p << 4)  & 0x07f00000u) * S;
    a3 += __uint_as_float((p >> 4)  & 0x07f00000u) * S;
  }

  float inv = invdeg[wave];
  ushort4 o;
  o.x = f2bf(a0 * inv); o.y = f2bf(a1 * inv);
  o.z = f2bf(a2 * inv); o.w = f2bf(a3 * inv);
  *(ushort4*)(hn + (size_t)wave * 256 + lane * 4) = o;
}

// ---------- gather_add64: out[n,:] += invdeg * sum of Y3[src,:]  (64 fp32 cols) ----
__global__ __launch_bounds__(256)
void gather_add64(const unsigned short* __restrict__ Y3,
                  const int* __restrict__ start, const int* __restrict__ esrc,
                  const float* __restrict__ invdeg, float* __restrict__ out) {
  int wave = (int)((blockIdx.x * 256 + threadIdx.x) >> 6);
  if (wave >= N_NODES) return;
  int lane = threadIdx.x & 63;
  int slot = lane >> 4, l16 = lane & 15;
  int s0 = start[wave], s1 = start[wave + 1];
  const unsigned short* ybase = Y3 + 4 * l16;       // cols [4*l16, 4*l16+4)
  float a0 = 0.f, a1 = 0.f, a2 = 0.f, a3 = 0.f;
  int e = s0 + slot;
  for (; e + 12 < s1; e += 16) {                    // slots cover e, e+4, e+8, e+12
    int sn0 = esrc[e], sn1 = esrc[e + 4], sn2 = esrc[e + 8], sn3 = esrc[e + 12];
    uint2 p0 = *(const uint2*)(ybase + (size_t)sn0 * 64);
    uint2 p1 = *(const uint2*)(ybase + (size_t)sn1 * 64);
    uint2 p2 = *(const uint2*)(ybase + (size_t)sn2 * 64);
    uint2 p3 = *(const uint2*)(ybase + (size_t)sn3 * 64);
    a0 += bf_lo(p0.x) + bf_lo(p1.x) + bf_lo(p2.x) + bf_lo(p3.x);
    a1 += bf_hi(p0.x) + bf_hi(p1.x) + bf_hi(p2.x) + bf_hi(p3.x);
    a2 += bf_lo(p0.y) + bf_lo(p1.y) + bf_lo(p2.y) + bf_lo(p3.y);
    a3 += bf_hi(p0.y) + bf_hi(p1.y) + bf_hi(p2.y) + bf_hi(p3.y);
  }
  for (; e < s1; e += 4) {                          // 4-slot-parallel tail
    uint2 p = *(const uint2*)(ybase + (size_t)esrc[e] * 64);
    a0 += bf_lo(p.x); a1 += bf_hi(p.x);
    a2 += bf_lo(p.y); a3 += bf_hi(p.y);
  }
  a0 += __shfl_xor(a0, 16, 64); a1 += __shfl_xor(a1, 16, 64);
  a2 += __shfl_xor(a2, 16, 64); a3 += __shfl_xor(a3, 16, 64);
  a0 += __shfl_xor(a0, 32, 64); a1 += __shfl_xor(a1, 32, 64);
  a2 += __shfl_xor(a2, 32, 64); a3 += __shfl_xor(a3, 32, 64);
  if (slot == 0) {
    float inv = invdeg[wave];
    float4* q = (float4*)(out + (size_t)wave * 64 + 4 * l16);
    float4 v = *q;
    v.x += inv * a0; v.y += inv * a1; v.z += inv * a2; v.w += inv * a3;
    *q = v;
  }
}

// ---------- LDS double-buffered fused GEMM ----------
// BN=128, N-block fastest-varying (pair-adjacent for A-panel L2 reuse).
// MODE 0: out = [H | HN] @ Wb^T + bias (optional relu), K = 2D.
//   If y3 != nullptr (layer 1): also write fp8 e4m3 copy of the post-relu output
//   to y3 (bit-manip encode) for the next layer's fp8 gather.
// MODE 1: K = D (reads H only); cols 0-63 -> d_out fp32 (+bias), 64-127 -> Y3 bf16.
template<int D, int DOUT, int BN, bool RELU, bool OUTF32, int MODE>
__global__ __launch_bounds__(256)
void sage_gemm(const unsigned short* __restrict__ H,
               const unsigned short* __restrict__ HN,
               const unsigned short* __restrict__ Wb,
               const float* __restrict__ bias,
               void* __restrict__ outp,
               unsigned short* __restrict__ y3) {
  constexpr int K   = (MODE == 1) ? D : 2 * D;
  constexpr int BM  = 128, KC = 32;
  constexpr int NCHUNK = K / KC;
  constexpr int AF  = BM / 16;
  constexpr int BF  = BN / 16;
  constexpr int FR  = AF + BF;
  constexpr int NMF = 4;
  constexpr int NJF = BF / 2;

  __shared__ __align__(16) unsigned short lds0[FR * 512];
  __shared__ __align__(16) unsigned short lds1[FR * 512];

  const int tid  = threadIdx.x;
  const int wave = tid >> 6, lane = tid & 63;
  const int l16  = lane & 15, quad = lane >> 4;
  const int n0   = blockIdx.y * BM;      // M-tile on y (slow)
  const int bn0  = blockIdx.x * BN;      // N-block on x (fast -> pair adjacent)
  const int wm   = wave >> 1, wn = wave & 1;

  floatx4 acc[NMF][NJF] = {};

  auto stage = [&](int c, unsigned short* buf) {
    const int kc = c * KC;
    const unsigned short* srcH = (kc < D) ? H : HN;
    const int kb = (kc < D) ? kc : kc - D;
    const int w0 = __builtin_amdgcn_readfirstlane(wave);
#pragma unroll
    for (int i = 0; i < FR / 4; ++i) {
      const int fu = w0 + 4 * i;
      const unsigned short* g;
      if (fu < AF) {
        int row = min(n0 + fu * 16 + l16, N_NODES - 1);
        g = srcH + (size_t)row * D + kb + quad * 8;
      } else {
        int col = bn0 + (fu - AF) * 16 + l16;
        g = Wb + (size_t)col * K + kc + quad * 8;
      }
      __builtin_amdgcn_global_load_lds(
          (const __attribute__((address_space(1))) unsigned int*)g,
          (__attribute__((address_space(3))) unsigned int*)(buf + fu * 512),
          16, 0, 0);
    }
  };

  auto compute = [&](const unsigned short* buf) {
    short8 b[NJF];
#pragma unroll
    for (int jt = 0; jt < NJF; ++jt)
      b[jt] = *(const short8*)(buf + (AF + wn * NJF + jt) * 512 + lane * 8);
#pragma unroll
    for (int mi = 0; mi < NMF; ++mi) {
      short8 a = *(const short8*)(buf + (wm * NMF + mi) * 512 + lane * 8);
#pragma unroll
      for (int jt = 0; jt < NJF; ++jt)
        acc[mi][jt] = __builtin_amdgcn_mfma_f32_16x16x32_bf16(a, b[jt], acc[mi][jt], 0, 0, 0);
    }
  };

  stage(0, lds0);
  __syncthreads();
#pragma unroll 1
  for (int c = 0; c < NCHUNK; c += 2) {
    stage(c + 1, lds1);
    compute(lds0);
    __syncthreads();
    if (c + 2 < NCHUNK) stage(c + 2, lds0);
    compute(lds1);
    __syncthreads();
  }

#pragma unroll
  for (int mi = 0; mi < NMF; ++mi) {
#pragma unroll
    for (int jt = 0; jt < NJF; ++jt) {
      int j = bn0 + wn * (NJF * 16) + jt * 16 + l16;
      float bj = (MODE == 1 && wn == 1) ? 0.0f : bias[j];
#pragma unroll
      for (int r = 0; r < 4; ++r) {
        int node = n0 + wm * 64 + mi * 16 + quad * 4 + r;
        if (node < N_NODES) {
          float v = acc[mi][jt][r];
          if constexpr (MODE == 1) {
            if (wn == 0) ((float*)outp)[(size_t)node * 64 + j] = v + bj;
            else y3[(size_t)node * 64 + (j - 64)] = f2bf(v);
          } else {
            v += bj;
            if (RELU) v = fmaxf(v, 0.0f);
            if (OUTF32) ((float*)outp)[(size_t)node * DOUT + j] = v;
            else {
              ((unsigned short*)outp)[(size_t)node * DOUT + j] = f2bf(v);
              if (y3 != nullptr)       // fp8 side-copy for next-layer gather
                ((unsigned char*)y3)[(size_t)node * DOUT + j] = (unsigned char)f2fp8_pos(v);
            }
          }
        }
      }
    }
  }
}

extern "C" void kernel_launch(void* const* d_in, const int* in_sizes, int n_in,
                              void* d_out, int out_size, void* d_ws, size_t ws_size,
                              hipStream_t stream) {
  const float* x   = (const float*)d_in[0];
  const int*   src = (const int*)d_in[1];
  const int*   dst = (const int*)d_in[2];
  const float* W1 = (const float*)d_in[3];
  const float* b1 = (const float*)d_in[4];
  const float* W2 = (const float*)d_in[5];
  const float* b2 = (const float*)d_in[6];
  const float* W3 = (const float*)d_in[7];
  const float* b3 = (const float*)d_in[8];

  char* ws = (char*)d_ws;
  unsigned short* H0 = (unsigned short*)ws; ws += (size_t)N_NODES * 128 * 2; // 25.6 MB
  unsigned short* H1 = (unsigned short*)ws; ws += (size_t)N_NODES * 256 * 2; // 51.2 MB
  // H1q (fp8 copy of H1, 25.6 MB) aliases H2's region: GEMM1 writes H1q,
  // gather_mean_fp8 reads it, THEN GEMM2 overwrites H2 (stream-ordered, disjoint
  // lifetimes). Keeps total workspace identical to the verified R9 footprint.
  unsigned char*  H1q = (unsigned char*)ws;
  unsigned short* H2 = (unsigned short*)ws; ws += (size_t)N_NODES * 256 * 2; // 51.2 MB
  unsigned short* HN = (unsigned short*)ws; ws += (size_t)N_NODES * 256 * 2; // 51.2 MB
  unsigned int* staging = (unsigned int*)ws; ws += (size_t)N_EDGES * 4;      // 6.4 MB (packed)
  int* esrc   = (int*)ws;  ws += (size_t)N_EDGES * 4;                        // 6.4 MB
  int* startp = (int*)ws;  ws += (size_t)(N_NODES + 32) * 4;
  float* invdeg = (float*)ws; ws += (size_t)(N_NODES + 32) * 4;
  int* bucketBase  = (int*)ws; ws += (NBUCK + 32) * 4;
  int* bucketCount = (int*)ws; ws += NBUCK * 4;
  int* blockHist   = (int*)ws; ws += (size_t)NB_E * NBUCK * 4;   // 400 KB
  int* blockOfs    = (int*)ws; ws += (size_t)NB_E * NBUCK * 4;   // 400 KB
  unsigned short* Y3 = (unsigned short*)ws; ws += (size_t)N_NODES * 64 * 2;  // 12.8 MB
  unsigned short* Wb1 = (unsigned short*)ws; ws += 256 * 256 * 2;
  unsigned short* Wb2 = (unsigned short*)ws; ws += 256 * 512 * 2;
  unsigned short* Wb3 = (unsigned short*)ws; ws += 128 * 256 * 2;

  // CSR build: histogram -> 2-level scan -> {staging scatter || bf16 cvts} -> sort
  pass1a_kernel<<<NB_E, 256, 0, stream>>>(dst, blockHist);
  scanB1_kernel<<<(NBUCK * 64 + 255) / 256, 256, 0, stream>>>(blockHist, blockOfs, bucketCount);
  scanB2_kernel<<<1, NBUCK, 0, stream>>>(bucketCount, bucketBase);
  mid_kernel<<<MID_END, 256, 0, stream>>>(src, dst, blockOfs, bucketBase, staging,
                                          x, H0, W1, Wb1, W2, Wb2, W3, Wb3);
  pass2_kernel<<<NBUCK, 512, 0, stream>>>(staging, bucketBase, startp, invdeg, esrc);

  const int GGRID = (N_NODES * 64 + 255) / 256;    // one wave per node
  const int MG = (N_NODES + 127) / 128;            // 782 M-tiles

  // ---- layer 1: D=128 -> 256, relu (also emits fp8 copy of H1 into H2's region) ----
  gather_mean<128><<<GGRID, 256, 0, stream>>>(H0, startp, esrc, invdeg, HN);
  sage_gemm<128, 256, 128, true, false, 0><<<dim3(2, MG), 256, 0, stream>>>(H0, HN, Wb1, b1, H1, (unsigned short*)H1q);

  // ---- layer 2: D=256 -> 256, relu (gather over fp8 H1 copy; GEMM2 then
  //      overwrites the aliased region with H2) ----
  gather_mean_fp8<<<GGRID, 256, 0, stream>>>(H1q, startp, esrc, invdeg, HN);
  sage_gemm<256, 256, 128, true, false, 0><<<dim3(2, MG), 256, 0, stream>>>(H1, HN, Wb2, b2, H2, nullptr);

  // ---- layer 3 (aggregate after GEMM): dual GEMM then edge-mean on 64 cols ----
  sage_gemm<256, 128, 128, false, true, 1><<<dim3(1, MG), 256, 0, stream>>>(H2, nullptr, Wb3, b3, (float*)d_out, Y3);
  gather_add64<<<GGRID, 256, 0, stream>>>(Y3, startp, esrc, invdeg, (float*)d_out);
}